// Round 4
// baseline (7391.218 us; speedup 1.0000x reference)
//
#include <hip/hip_runtime.h>
#include <hip/hip_bf16.h>

#define N_FEA   3145728   // 2*96*128*128
#define N_EN    196608    // 2*96*32*32
#define N_E1    786432    // 2*96*64*64
#define OUT_EN  3145728
#define OUT_Q   3342336

__device__ __forceinline__ float tap9(const float* __restrict__ pl, int iy0, int ix0,
                                      int Hin, int Win, const float* wv) {
    float a = 0.f;
#pragma unroll
    for (int ky = 0; ky < 3; ++ky) {
        int iy = iy0 + ky;
        if ((unsigned)iy >= (unsigned)Hin) continue;
        const float* row = pl + (long)iy * Win;
#pragma unroll
        for (int kx = 0; kx < 3; ++kx) {
            int ix = ix0 + kx;
            if ((unsigned)ix >= (unsigned)Win) continue;
            a = fmaf(row[ix], wv[ky * 3 + kx], a);
        }
    }
    return a;
}

// Direct 3x3 conv, pad=1, stride 1|2, virtual concat (in0:c0, in1:c1). fp32.
__global__ void conv3x3_k(const float* __restrict__ in0, int c0,
                          const float* __restrict__ in1, int c1,
                          const float* __restrict__ w, const float* __restrict__ bias,
                          float* __restrict__ out,
                          int Cout, int Hin, int Win, int stride, int relu) {
    int Hout = (Hin - 1) / stride + 1, Wout = (Win - 1) / stride + 1;
    long total = 2L * Cout * Hout * Wout;
    long idx = (long)blockIdx.x * blockDim.x + threadIdx.x;
    if (idx >= total) return;
    int ox = (int)(idx % Wout);
    long t = idx / Wout;
    int oy = (int)(t % Hout); t /= Hout;
    int oc = (int)(t % Cout);
    int b = (int)(t / Cout);
    int Cin = c0 + c1;
    float acc = bias[oc];
    int iy0 = oy * stride - 1, ix0 = ox * stride - 1;
    const float* wrow = w + (long)oc * Cin * 9;
    for (int c = 0; c < Cin; ++c) {
        float wv[9];
#pragma unroll
        for (int k = 0; k < 9; ++k) wv[k] = wrow[(long)c * 9 + k];
        const float* pl = (c < c0)
            ? in0 + ((long)b * c0 + c) * (long)Hin * Win
            : in1 + ((long)b * c1 + (c - c0)) * (long)Hin * Win;
        acc += tap9(pl, iy0, ix0, Hin, Win, wv);
    }
    if (relu) acc = acc > 0.f ? acc : 0.1f * acc;
    out[idx] = acc;
}

// ConvTranspose2d(96->96,k3,s2,p1,op1) gather form; w layout [Cin,Cout,3,3].
__global__ void convt3x3_k(const float* __restrict__ in, const float* __restrict__ w,
                           const float* __restrict__ bias, float* __restrict__ out,
                           int Hin, int Win, int relu) {
    const int C = 96;
    int Hout = 2 * Hin, Wout = 2 * Win;
    long total = 2L * C * Hout * Wout;
    long idx = (long)blockIdx.x * blockDim.x + threadIdx.x;
    if (idx >= total) return;
    int ox = (int)(idx % Wout);
    long t = idx / Wout;
    int oy = (int)(t % Hout); t /= Hout;
    int oc = (int)(t % C);
    int b = (int)(t / C);
    float acc = bias[oc];
    for (int c = 0; c < C; ++c) {
        const float* pl = in + ((long)b * C + c) * (long)Hin * Win;
        const float* wp = w + ((long)c * C + oc) * 9;
#pragma unroll
        for (int ky = 0; ky < 3; ++ky) {
            int ty = oy + 1 - ky;      // need ty = 2*iy
            if (ty & 1) continue;      // also rejects ty == -1
            int iy = ty >> 1;
            if ((unsigned)iy >= (unsigned)Hin) continue;
#pragma unroll
            for (int kx = 0; kx < 3; ++kx) {
                int tx = ox + 1 - kx;
                if (tx & 1) continue;
                int ix = tx >> 1;
                if ((unsigned)ix >= (unsigned)Win) continue;
                acc = fmaf(pl[(long)iy * Win + ix], wp[ky * 3 + kx], acc);
            }
        }
    }
    if (relu) acc = acc > 0.f ? acc : 0.1f * acc;
    out[idx] = acc;
}

// en -> outputs 1 & 2 (fp32) + fp32 q for the decoder. rintf = half-even = jnp.round.
__global__ void quant_k(const float* __restrict__ en, float* __restrict__ out_en,
                        float* __restrict__ out_q, float* __restrict__ qf, int n) {
    int i = blockIdx.x * 256 + threadIdx.x;
    if (i >= n) return;
    float e = en[i];
    float q = rintf(e);
    out_en[i] = e;
    out_q[i] = q;
    qf[i] = q;
}

// Fused offset-conv + DCNv1. Block = one (b, oy) x 4 consecutive ox.
// Phase 0: stage de 3-row x 6-col x 96-ch tile into LDS.
// Phase 1: offset conv (144 ch x 4 px), each value used exactly once -> no redundancy.
// Phase 2: bilinear-sample 4*96*9 taps into LDS.
// Phase 3: threads 0..95 contract over 864 taps with dcn_w.
__global__ __launch_bounds__(128) void deform_fused_k(
    const float* __restrict__ x, const float* __restrict__ de,
    const float* __restrict__ cw, const float* __restrict__ cb,
    const float* __restrict__ dw, const float* __restrict__ db,
    float* __restrict__ out) {
    const int H = 128, W = 128, C = 96, TX = 4;
    __shared__ float deL[96 * 18];        // [c][ry 0..2][cx 0..5]
    __shared__ float offL[TX][144];
    __shared__ float s[TX][864];
    int bid = blockIdx.x;
    int oxb = (bid % (W / TX)) * TX; bid /= (W / TX);
    int oy = bid % H;
    int b = bid / H;
    int tid = threadIdx.x;
    // phase 0: stage de tile (zero-padded)
    for (int e = tid; e < 96 * 18; e += 128) {
        int c = e / 18, r = e % 18, ry = r / 6, cx = r % 6;
        int iy = oy - 1 + ry, ix = oxb - 1 + cx;
        float v = 0.f;
        if ((unsigned)iy < (unsigned)H && (unsigned)ix < (unsigned)W)
            v = de[((long)(b * C + c) * H + iy) * W + ix];
        deL[e] = v;
    }
    __syncthreads();
    // phase 1: offset conv. thread -> offset channel cc; all 4 px share weight row.
    for (int cc = tid; cc < 144; cc += 128) {
        float bz = cb[cc];
        float a0 = bz, a1 = bz, a2 = bz, a3 = bz;
        const float* wr = cw + (long)cc * C * 9;
        for (int c = 0; c < C; ++c) {
            const float* dl = deL + c * 18;
#pragma unroll
            for (int ky = 0; ky < 3; ++ky) {
#pragma unroll
                for (int kx = 0; kx < 3; ++kx) {
                    float wv = wr[c * 9 + ky * 3 + kx];
                    const float* dr = dl + ky * 6 + kx;
                    a0 = fmaf(dr[0], wv, a0);
                    a1 = fmaf(dr[1], wv, a1);
                    a2 = fmaf(dr[2], wv, a2);
                    a3 = fmaf(dr[3], wv, a3);
                }
            }
        }
        offL[0][cc] = a0; offL[1][cc] = a1; offL[2][cc] = a2; offL[3][cc] = a3;
    }
    __syncthreads();
    // phase 2: bilinear sampling
    for (int e = tid; e < TX * 864; e += 128) {
        int p = e / 864, r = e % 864;
        int c = r / 9, kk = r % 9, g = c / 12;
        int ox = oxb + p;
        float offy = offL[p][g * 18 + kk * 2];
        float offx = offL[p][g * 18 + kk * 2 + 1];
        float py = (float)(oy + kk / 3 - 1) + offy;
        float px = (float)(ox + kk % 3 - 1) + offx;
        float y0f = floorf(py), x0f = floorf(px);
        float ly = py - y0f, lx = px - x0f;
        int y0 = (int)y0f, x0 = (int)x0f;
        const float* pl = x + ((long)b * C + c) * (long)H * W;
        float w00 = (1.f - ly) * (1.f - lx), w01 = (1.f - ly) * lx;
        float w10 = ly * (1.f - lx), w11 = ly * lx;
        float v = 0.f;
        if ((unsigned)y0 < (unsigned)H && (unsigned)x0 < (unsigned)W)
            v = fmaf(pl[y0 * W + x0], w00, v);
        if ((unsigned)y0 < (unsigned)H && (unsigned)(x0 + 1) < (unsigned)W)
            v = fmaf(pl[y0 * W + x0 + 1], w01, v);
        if ((unsigned)(y0 + 1) < (unsigned)H && (unsigned)x0 < (unsigned)W)
            v = fmaf(pl[(y0 + 1) * W + x0], w10, v);
        if ((unsigned)(y0 + 1) < (unsigned)H && (unsigned)(x0 + 1) < (unsigned)W)
            v = fmaf(pl[(y0 + 1) * W + x0 + 1], w11, v);
        s[p][c * 9 + kk] = v;
    }
    __syncthreads();
    // phase 3: contraction
    if (tid < C) {
        int oc = tid;
        float bz = db[oc];
        float a0 = bz, a1 = bz, a2 = bz, a3 = bz;
        const float* wp = dw + (long)oc * 864;
        for (int i = 0; i < 864; ++i) {
            float wv = wp[i];
            a0 = fmaf(s[0][i], wv, a0);
            a1 = fmaf(s[1][i], wv, a1);
            a2 = fmaf(s[2][i], wv, a2);
            a3 = fmaf(s[3][i], wv, a3);
        }
        long ob = (((long)b * C + oc) * H + oy) * W + oxb;
        out[ob + 0] = a0; out[ob + 1] = a1; out[ob + 2] = a2; out[ob + 3] = a3;
    }
}

// out = alg + lrelu(conv3x3(r1, ref2)). alg may alias out (elementwise only).
__global__ void conv_add_k(const float* __restrict__ r1, const float* __restrict__ alg,
                           const float* __restrict__ w, const float* __restrict__ bias,
                           float* __restrict__ out) {
    const int C = 96, H = 128, W = 128;
    long idx = (long)blockIdx.x * blockDim.x + threadIdx.x;
    if (idx >= (long)N_FEA) return;
    int ox = (int)(idx % W);
    long t = idx / W;
    int oy = (int)(t % H); t /= H;
    int oc = (int)(t % C);
    int b = (int)(t / C);
    float acc = bias[oc];
    int iy0 = oy - 1, ix0 = ox - 1;
    const float* wrow = w + (long)oc * C * 9;
    for (int c = 0; c < C; ++c) {
        float wv[9];
#pragma unroll
        for (int k = 0; k < 9; ++k) wv[k] = wrow[(long)c * 9 + k];
        acc += tap9(r1 + ((long)b * C + c) * (long)H * W, iy0, ix0, H, W, wv);
    }
    acc = acc > 0.f ? acc : 0.1f * acc;
    out[idx] = alg[idx] + acc;
}

extern "C" void kernel_launch(void* const* d_in, const int* in_sizes, int n_in,
                              void* d_out, int out_size, void* d_ws, size_t ws_size,
                              hipStream_t stream) {
    const float* ref_fea = (const float*)d_in[0];
    const float* inp_fea = (const float*)d_in[1];
    const float* oc1_w = (const float*)d_in[2];  const float* oc1_b = (const float*)d_in[3];
    const float* oc3_w = (const float*)d_in[4];  const float* oc3_b = (const float*)d_in[5];
    const float* enc1_w = (const float*)d_in[6]; const float* enc1_b = (const float*)d_in[7];
    const float* enc2_w = (const float*)d_in[8]; const float* enc2_b = (const float*)d_in[9];
    const float* dec1_w = (const float*)d_in[10]; const float* dec1_b = (const float*)d_in[11];
    const float* dec2_w = (const float*)d_in[12]; const float* dec2_b = (const float*)d_in[13];
    const float* coff_w = (const float*)d_in[14]; const float* coff_b = (const float*)d_in[15];
    const float* dcn_w = (const float*)d_in[16];  const float* dcn_b = (const float*)d_in[17];
    const float* ref1_w = (const float*)d_in[18]; const float* ref1_b = (const float*)d_in[19];
    const float* ref2_w = (const float*)d_in[20]; const float* ref2_b = (const float*)d_in[21];

    float* out = (float*)d_out;
    // Slot S1 always in ws; slot S2 in ws if it fits, else the out0 region of d_out.
    float* S1 = (float*)d_ws;
    bool two_slots = ws_size >= (size_t)2 * N_FEA * sizeof(float);
    float* S2 = two_slots ? (S1 + N_FEA) : out;
    float* E = S1 + N_E1;          // en fp32 (within S1, after e1 region)
    float* F = E + N_EN;           // q fp32

    dim3 blk(256);
    auto nb = [](long n) { return dim3((unsigned)((n + 255) / 256)); };

    // 1. t1 = lrelu(conv(cat(ref,inp), oc1)) -> S1
    conv3x3_k<<<nb(N_FEA), blk, 0, stream>>>(ref_fea, 96, inp_fea, 96, oc1_w, oc1_b,
                                             S1, 96, 128, 128, 1, 1);
    // 2. t2 = lrelu(conv(t1, oc3)) -> S2
    conv3x3_k<<<nb(N_FEA), blk, 0, stream>>>(S1, 96, S1, 0, oc3_w, oc3_b,
                                             S2, 96, 128, 128, 1, 1);
    // 3. e1 = lrelu(conv_s2(t2, enc1)) -> S1[0..N_E1)
    conv3x3_k<<<nb(N_E1), blk, 0, stream>>>(S2, 96, S2, 0, enc1_w, enc1_b,
                                            S1, 96, 128, 128, 2, 1);
    // 4. en = conv_s2(e1, enc2) -> E
    conv3x3_k<<<nb(N_EN), blk, 0, stream>>>(S1, 96, S1, 0, enc2_w, enc2_b,
                                            E, 96, 64, 64, 2, 0);
    // 5. outputs 1/2 + q fp32 -> F
    quant_k<<<nb(N_EN), blk, 0, stream>>>(E, out + OUT_EN, out + OUT_Q, F, N_EN);
    // 6. d1 = lrelu(convT(q, dec1)) -> S2[0..N_E1)
    convt3x3_k<<<nb(N_E1), blk, 0, stream>>>(F, dec1_w, dec1_b, S2, 32, 32, 1);
    // 7. de = convT(d1, dec2) -> S1
    convt3x3_k<<<nb(N_FEA), blk, 0, stream>>>(S2, dec2_w, dec2_b, S1, 64, 64, 0);
    // 8. aligned = deform(ref_fea, offconv(de)) -> S2
    deform_fused_k<<<dim3(2 * 128 * 32), dim3(128), 0, stream>>>(ref_fea, S1, coff_w, coff_b,
                                                                 dcn_w, dcn_b, S2);
    // 9. r1 = lrelu(conv(cat(aligned, ref_fea), ref1)) -> S1
    conv3x3_k<<<nb(N_FEA), blk, 0, stream>>>(S2, 96, ref_fea, 96, ref1_w, ref1_b,
                                             S1, 96, 128, 128, 1, 1);
    // 10. out0 = aligned + lrelu(conv(r1, ref2))
    conv_add_k<<<nb(N_FEA), blk, 0, stream>>>(S1, S2, ref2_w, ref2_b, out);
}

// Round 5
// 4127.654 us; speedup vs baseline: 1.7907x; 1.7907x over previous
//
#include <hip/hip_runtime.h>
#include <hip/hip_bf16.h>

#define N_FEA   3145728   // 2*96*128*128
#define N_EN    196608    // 2*96*32*32
#define N_E1    786432    // 2*96*64*64
#define OUT_EN  3145728
#define OUT_Q   3342336

// Direct 3x3 conv, pad=1, stride S, virtual concat (in0:c0, in1:c1).
// Block = one (b, oc, strip of 1024 output px); thread = 4 consecutive ox.
// Weights for this oc staged in LDS; inputs loaded as contiguous runs (vectorizable).
template <int S>
__global__ __launch_bounds__(256) void conv3x3_v2(
    const float* __restrict__ in0, int c0,
    const float* __restrict__ in1, int c1,
    const float* __restrict__ w, const float* __restrict__ bias,
    const float* __restrict__ addsrc,   // if non-null: out = addsrc + act(conv)
    float* __restrict__ out,
    int Cout, int Hin, int Win, int relu) {
    const int Hout = (Hin - 1) / S + 1, Wout = (Win - 1) / S + 1;
    const int strips = (Hout * Wout) / 1024;
    int bid = blockIdx.x;
    const int strip = bid % strips; bid /= strips;
    const int oc = bid % Cout;
    const int b = bid / Cout;
    const int Cin = c0 + c1;
    __shared__ float wl[1728];          // up to 192 ch * 9
    for (int i = threadIdx.x; i < Cin * 9; i += 256)
        wl[i] = w[(long)oc * Cin * 9 + i];
    __syncthreads();
    const int pix = strip * 1024 + threadIdx.x * 4;
    const int oy = pix / Wout, oxb = pix % Wout;
    const int iy0 = oy * S - 1, ixb = oxb * S - 1;
    constexpr int NX = 3 * S + 3;       // input cols spanned by 4 outputs
    float acc[4];
    const float bz = bias[oc];
#pragma unroll
    for (int j = 0; j < 4; ++j) acc[j] = bz;
    const bool fast = (ixb >= 0) && (ixb + NX - 1 < Win);

    auto seg = [&](const float* base, int nc, int wofs) {
        const float* pl = base + (long)b * nc * Hin * Win;
        for (int c = 0; c < nc; ++c) {
            float wv[9];
#pragma unroll
            for (int k = 0; k < 9; ++k) wv[k] = wl[(wofs + c) * 9 + k];
#pragma unroll
            for (int ky = 0; ky < 3; ++ky) {
                int iy = iy0 + ky;
                if ((unsigned)iy >= (unsigned)Hin) continue;
                const float* row = pl + (long)iy * Win + ixb;
                float r[NX];
                if (fast) {
#pragma unroll
                    for (int i = 0; i < NX; ++i) r[i] = row[i];
                } else {
#pragma unroll
                    for (int i = 0; i < NX; ++i) {
                        int col = ixb + i;
                        r[i] = ((unsigned)col < (unsigned)Win) ? row[i] : 0.f;
                    }
                }
#pragma unroll
                for (int j = 0; j < 4; ++j)
#pragma unroll
                    for (int kx = 0; kx < 3; ++kx)
                        acc[j] = fmaf(r[j * S + kx], wv[ky * 3 + kx], acc[j]);
            }
            pl += (long)Hin * Win;
        }
    };
    seg(in0, c0, 0);
    seg(in1, c1, c0);

    long idx = (((long)b * Cout + oc) * Hout + oy) * Wout + oxb;
#pragma unroll
    for (int j = 0; j < 4; ++j) {
        float a = acc[j];
        if (relu) a = a > 0.f ? a : 0.1f * a;
        if (addsrc) a += addsrc[idx + j];
        out[idx + j] = a;
    }
}

// ConvTranspose2d(96->96,k3,s2,p1,op1), gather form, 4 ox per thread.
// For oxb even: per valid row iy, needs input cols c0x..c0x+2 (c0x=oxb/2):
//   acc0 += r0*w[ky,1];  acc1 += r1*w[ky,0] + r0*w[ky,2];
//   acc2 += r1*w[ky,1];  acc3 += r2*w[ky,0] + r1*w[ky,2];
__global__ __launch_bounds__(256) void convt3x3_v2(
    const float* __restrict__ in, const float* __restrict__ w,
    const float* __restrict__ bias, float* __restrict__ out,
    int Hin, int Win, int relu) {
    const int C = 96;
    const int Hout = 2 * Hin, Wout = 2 * Win;
    const int strips = (Hout * Wout) / 1024;
    int bid = blockIdx.x;
    const int strip = bid % strips; bid /= strips;
    const int oc = bid % C;
    const int b = bid / C;
    __shared__ float wl[864];
    for (int i = threadIdx.x; i < C * 9; i += 256) {
        int c = i / 9, k = i % 9;
        wl[i] = w[((long)c * C + oc) * 9 + k];
    }
    __syncthreads();
    const int pix = strip * 1024 + threadIdx.x * 4;
    const int oy = pix / Wout, oxb = pix % Wout;
    const int c0x = oxb >> 1;
    const int oyE = oy + 1;
    float acc[4];
    const float bz = bias[oc];
#pragma unroll
    for (int j = 0; j < 4; ++j) acc[j] = bz;
    const bool r2ok = (c0x + 2) < Win;

    const float* pl = in + (long)b * C * Hin * Win;
    for (int c = 0; c < C; ++c) {
        float wv[9];
#pragma unroll
        for (int k = 0; k < 9; ++k) wv[k] = wl[c * 9 + k];
#pragma unroll
        for (int ky = 0; ky < 3; ++ky) {
            int ty = oyE - ky;
            if (ty & 1) continue;
            int iy = ty >> 1;
            if ((unsigned)iy >= (unsigned)Hin) continue;
            const float* row = pl + (long)iy * Win + c0x;
            float r0 = row[0];
            float r1 = row[1];
            float r2 = r2ok ? row[2] : 0.f;
            acc[0] = fmaf(r0, wv[ky * 3 + 1], acc[0]);
            acc[1] = fmaf(r1, wv[ky * 3 + 0], acc[1]);
            acc[1] = fmaf(r0, wv[ky * 3 + 2], acc[1]);
            acc[2] = fmaf(r1, wv[ky * 3 + 1], acc[2]);
            acc[3] = fmaf(r2, wv[ky * 3 + 0], acc[3]);
            acc[3] = fmaf(r1, wv[ky * 3 + 2], acc[3]);
        }
        pl += (long)Hin * Win;
    }
    long idx = (((long)b * C + oc) * Hout + oy) * Wout + oxb;
#pragma unroll
    for (int j = 0; j < 4; ++j) {
        float a = acc[j];
        if (relu) a = a > 0.f ? a : 0.1f * a;
        out[idx + j] = a;
    }
}

// en -> outputs 1 & 2 (fp32) + fp32 q for the decoder. rintf = half-even = jnp.round.
__global__ void quant_k(const float* __restrict__ en, float* __restrict__ out_en,
                        float* __restrict__ out_q, float* __restrict__ qf, int n) {
    int i = blockIdx.x * 256 + threadIdx.x;
    if (i >= n) return;
    float e = en[i];
    float q = rintf(e);
    out_en[i] = e;
    out_q[i] = q;
    qf[i] = q;
}

// Fused offset-conv + DCNv1. Block = one (b, oy) x 4 consecutive ox.
__global__ __launch_bounds__(128) void deform_fused_k(
    const float* __restrict__ x, const float* __restrict__ de,
    const float* __restrict__ cw, const float* __restrict__ cb,
    const float* __restrict__ dw, const float* __restrict__ db,
    float* __restrict__ out) {
    const int H = 128, W = 128, C = 96, TX = 4;
    __shared__ float deL[96 * 18];        // [c][ry 0..2][cx 0..5]
    __shared__ float offL[TX][144];
    __shared__ float s[TX][864];
    int bid = blockIdx.x;
    int oxb = (bid % (W / TX)) * TX; bid /= (W / TX);
    int oy = bid % H;
    int b = bid / H;
    int tid = threadIdx.x;
    for (int e = tid; e < 96 * 18; e += 128) {
        int c = e / 18, r = e % 18, ry = r / 6, cx = r % 6;
        int iy = oy - 1 + ry, ix = oxb - 1 + cx;
        float v = 0.f;
        if ((unsigned)iy < (unsigned)H && (unsigned)ix < (unsigned)W)
            v = de[((long)(b * C + c) * H + iy) * W + ix];
        deL[e] = v;
    }
    __syncthreads();
    for (int cc = tid; cc < 144; cc += 128) {
        float bz = cb[cc];
        float a0 = bz, a1 = bz, a2 = bz, a3 = bz;
        const float* wr = cw + (long)cc * C * 9;
        for (int c = 0; c < C; ++c) {
            const float* dl = deL + c * 18;
#pragma unroll
            for (int ky = 0; ky < 3; ++ky) {
#pragma unroll
                for (int kx = 0; kx < 3; ++kx) {
                    float wv = wr[c * 9 + ky * 3 + kx];
                    const float* dr = dl + ky * 6 + kx;
                    a0 = fmaf(dr[0], wv, a0);
                    a1 = fmaf(dr[1], wv, a1);
                    a2 = fmaf(dr[2], wv, a2);
                    a3 = fmaf(dr[3], wv, a3);
                }
            }
        }
        offL[0][cc] = a0; offL[1][cc] = a1; offL[2][cc] = a2; offL[3][cc] = a3;
    }
    __syncthreads();
    for (int e = tid; e < TX * 864; e += 128) {
        int p = e / 864, r = e % 864;
        int c = r / 9, kk = r % 9, g = c / 12;
        int ox = oxb + p;
        float offy = offL[p][g * 18 + kk * 2];
        float offx = offL[p][g * 18 + kk * 2 + 1];
        float py = (float)(oy + kk / 3 - 1) + offy;
        float px = (float)(ox + kk % 3 - 1) + offx;
        float y0f = floorf(py), x0f = floorf(px);
        float ly = py - y0f, lx = px - x0f;
        int y0 = (int)y0f, x0 = (int)x0f;
        const float* pl = x + ((long)b * C + c) * (long)H * W;
        float w00 = (1.f - ly) * (1.f - lx), w01 = (1.f - ly) * lx;
        float w10 = ly * (1.f - lx), w11 = ly * lx;
        float v = 0.f;
        if ((unsigned)y0 < (unsigned)H && (unsigned)x0 < (unsigned)W)
            v = fmaf(pl[y0 * W + x0], w00, v);
        if ((unsigned)y0 < (unsigned)H && (unsigned)(x0 + 1) < (unsigned)W)
            v = fmaf(pl[y0 * W + x0 + 1], w01, v);
        if ((unsigned)(y0 + 1) < (unsigned)H && (unsigned)x0 < (unsigned)W)
            v = fmaf(pl[(y0 + 1) * W + x0], w10, v);
        if ((unsigned)(y0 + 1) < (unsigned)H && (unsigned)(x0 + 1) < (unsigned)W)
            v = fmaf(pl[(y0 + 1) * W + x0 + 1], w11, v);
        s[p][c * 9 + kk] = v;
    }
    __syncthreads();
    if (tid < C) {
        int oc = tid;
        float bz = db[oc];
        float a0 = bz, a1 = bz, a2 = bz, a3 = bz;
        const float* wp = dw + (long)oc * 864;
        for (int i = 0; i < 864; ++i) {
            float wv = wp[i];
            a0 = fmaf(s[0][i], wv, a0);
            a1 = fmaf(s[1][i], wv, a1);
            a2 = fmaf(s[2][i], wv, a2);
            a3 = fmaf(s[3][i], wv, a3);
        }
        long ob = (((long)b * C + oc) * H + oy) * W + oxb;
        out[ob + 0] = a0; out[ob + 1] = a1; out[ob + 2] = a2; out[ob + 3] = a3;
    }
}

extern "C" void kernel_launch(void* const* d_in, const int* in_sizes, int n_in,
                              void* d_out, int out_size, void* d_ws, size_t ws_size,
                              hipStream_t stream) {
    const float* ref_fea = (const float*)d_in[0];
    const float* inp_fea = (const float*)d_in[1];
    const float* oc1_w = (const float*)d_in[2];  const float* oc1_b = (const float*)d_in[3];
    const float* oc3_w = (const float*)d_in[4];  const float* oc3_b = (const float*)d_in[5];
    const float* enc1_w = (const float*)d_in[6]; const float* enc1_b = (const float*)d_in[7];
    const float* enc2_w = (const float*)d_in[8]; const float* enc2_b = (const float*)d_in[9];
    const float* dec1_w = (const float*)d_in[10]; const float* dec1_b = (const float*)d_in[11];
    const float* dec2_w = (const float*)d_in[12]; const float* dec2_b = (const float*)d_in[13];
    const float* coff_w = (const float*)d_in[14]; const float* coff_b = (const float*)d_in[15];
    const float* dcn_w = (const float*)d_in[16];  const float* dcn_b = (const float*)d_in[17];
    const float* ref1_w = (const float*)d_in[18]; const float* ref1_b = (const float*)d_in[19];
    const float* ref2_w = (const float*)d_in[20]; const float* ref2_b = (const float*)d_in[21];

    float* out = (float*)d_out;
    float* S1 = (float*)d_ws;
    bool two_slots = ws_size >= (size_t)2 * N_FEA * sizeof(float);
    float* S2 = two_slots ? (S1 + N_FEA) : out;   // out0 region as 2nd slot if needed
    float* E = S1 + N_E1;
    float* F = E + N_EN;

    dim3 blk(256);
    // grids: 2 batch * Cout * strips(=HW_out/1024)
    dim3 g_full(2 * 96 * 16);    // 128x128 out
    dim3 g_half(2 * 96 * 4);     // 64x64 out
    dim3 g_quar(2 * 96 * 1);     // 32x32 out

    // 1. t1 = lrelu(conv(cat(ref,inp), oc1)) -> S1
    conv3x3_v2<1><<<g_full, blk, 0, stream>>>(ref_fea, 96, inp_fea, 96, oc1_w, oc1_b,
                                              nullptr, S1, 96, 128, 128, 1);
    // 2. t2 = lrelu(conv(t1, oc3)) -> S2
    conv3x3_v2<1><<<g_full, blk, 0, stream>>>(S1, 96, S1, 0, oc3_w, oc3_b,
                                              nullptr, S2, 96, 128, 128, 1);
    // 3. e1 = lrelu(conv_s2(t2, enc1)) -> S1[0..N_E1)
    conv3x3_v2<2><<<g_half, blk, 0, stream>>>(S2, 96, S2, 0, enc1_w, enc1_b,
                                              nullptr, S1, 96, 128, 128, 1);
    // 4. en = conv_s2(e1, enc2) -> E
    conv3x3_v2<2><<<g_quar, blk, 0, stream>>>(S1, 96, S1, 0, enc2_w, enc2_b,
                                              nullptr, E, 96, 64, 64, 0);
    // 5. outputs 1/2 + q fp32 -> F
    quant_k<<<dim3((N_EN + 255) / 256), blk, 0, stream>>>(E, out + OUT_EN, out + OUT_Q,
                                                          F, N_EN);
    // 6. d1 = lrelu(convT(q, dec1)) -> S2[0..N_E1)
    convt3x3_v2<<<g_half, blk, 0, stream>>>(F, dec1_w, dec1_b, S2, 32, 32, 1);
    // 7. de = convT(d1, dec2) -> S1
    convt3x3_v2<<<g_full, blk, 0, stream>>>(S2, dec2_w, dec2_b, S1, 64, 64, 0);
    // 8. aligned = deform(ref_fea, offconv(de)) -> S2
    deform_fused_k<<<dim3(2 * 128 * 32), dim3(128), 0, stream>>>(ref_fea, S1, coff_w, coff_b,
                                                                 dcn_w, dcn_b, S2);
    // 9. r1 = lrelu(conv(cat(aligned, ref_fea), ref1)) -> S1
    conv3x3_v2<1><<<g_full, blk, 0, stream>>>(S2, 96, ref_fea, 96, ref1_w, ref1_b,
                                              nullptr, S1, 96, 128, 128, 1);
    // 10. out0 = aligned + lrelu(conv(r1, ref2))
    conv3x3_v2<1><<<g_full, blk, 0, stream>>>(S1, 96, S1, 0, ref2_w, ref2_b,
                                              S2, out, 96, 128, 128, 1);
}